// Round 11
// baseline (217.288 us; speedup 1.0000x reference)
//
#include <hip/hip_runtime.h>

typedef __attribute__((ext_vector_type(4))) float float4v;
typedef __attribute__((ext_vector_type(8))) short short8;
typedef __attribute__((ext_vector_type(16))) float f32x16;

#define C_IN 32
#define C_OUT 32
#define HH 224
#define WW 224
#define HW (HH * WW)
#define STRIPE 14                 // output rows per block; 224 = 16 stripes x 32 imgs = 512 blocks
#define RING_PX 226               // w = -1 .. 224 (halo columns at px 0 and 225)
#define PIX_STRIDE 80             // 64B data (32ch bf16) + 16B pad; conflict-free b128
#define ROW_BYTES (RING_PX * PIX_STRIDE)  // 18,080
#define NTHR 512

// fp32 -> bf16 bits, round-to-nearest-even
__device__ __forceinline__ short f2bf(float f) {
    unsigned u = __float_as_uint(f);
    u += 0x7FFFu + ((u >> 16) & 1u);
    return (short)(u >> 16);
}
// pack two bf16 (even ch in low half) into one dword
__device__ __forceinline__ unsigned pack2(float e, float o) {
    return (unsigned)(unsigned short)f2bf(e) | ((unsigned)(unsigned short)f2bf(o) << 16);
}

// R11 = R7's known-correct kernel with ONE change: the occupancy attribute.
// R9 audit found amdgpu_waves_per_eu(2,2)'s max=2 capped every round since R6
// at 8 waves/CU — R7's second block never co-resided (occupancy stuck at 21%).
// launch_bounds(512,4): min 4 waves/EU -> VGPR cap 128 >= 116 measured need
// (no spill; plain compiler-tracked loads so spills would be SAFE anyway —
// R10's corruption came from spilling inline-asm async-load outputs, removed here).
// LDS 54.2KB x 2 blocks = 108.5KB/CU -> genuinely 2 blocks (16 waves)/CU.
__global__ __launch_bounds__(NTHR, 4)
void conv3x3_rows(const float* __restrict__ X, const float* __restrict__ Wt,
                  const float* __restrict__ Bias, float* __restrict__ Y) {
    __shared__ __align__(16) char ring0[ROW_BYTES];
    __shared__ __align__(16) char ring1[ROW_BYTES];
    __shared__ __align__(16) char ring2[ROW_BYTES];   // 54,240 B total

    const int tid = threadIdx.x;
    const int lane = tid & 63;
    const int wid = tid >> 6;      // wave 0..7
    const int col = lane & 31;     // A: out-channel; B/C: pixel col
    const int khalf = lane >> 5;   // K-half of MFMA K=16 slice

    // --- W fragments (A operand: M=32 k_out, K=16 c-slice) ---
    short8 wfrag[18];
#pragma unroll
    for (int rs = 0; rs < 9; ++rs) {
#pragma unroll
        for (int ch = 0; ch < 2; ++ch) {
            short8 f;
#pragma unroll
            for (int j = 0; j < 8; ++j) {
                int c = ch * 16 + khalf * 8 + j;
                f[j] = f2bf(Wt[(col * C_IN + c) * 9 + rs]);  // W[k_out][c][r][s]
            }
            wfrag[rs * 2 + ch] = f;
        }
    }

    // --- Bias in C-fragment order: row(k_out) = (i&3) + 8*(i>>2) + 4*khalf ---
    f32x16 biasv;
#pragma unroll
    for (int i = 0; i < 16; ++i)
        biasv[i] = Bias[(i & 3) + 8 * (i >> 2) + 4 * khalf];

    // --- Staging geometry: unit u = w4*16 + cp (cp = channel-pair, w4 = 4px group) ---
    const int cp0 = tid & 15, w40 = tid >> 4;         // unit0 = tid (896 units total)
    const int t1 = tid + NTHR;
    const bool has1 = (tid < 896 - NTHR);             // threads 0..383 take a second unit
    const int cp1 = t1 & 15, w41 = t1 >> 4;
    const int ge0 = (2 * cp0) * HW + 4 * w40;         // float offsets from (n, hh) row base
    const int go0 = ge0 + HW;
    const int ge1 = (2 * cp1) * HW + 4 * w41;
    const int go1 = ge1 + HW;

    const int bid = blockIdx.x;
    const int n = bid >> 4;                // image
    const int h1 = (bid & 15) * STRIPE;    // stripe start row
    const float* Xn = X + n * C_IN * HW;

    float4v e0, o0, e1, o1;
    const short8 z8 = {0, 0, 0, 0, 0, 0, 0, 0};

#define LOAD_ROW(hh) do {                                          \
        const float* rp = Xn + (hh) * WW;                          \
        e0 = *(const float4v*)(rp + ge0);                          \
        o0 = *(const float4v*)(rp + go0);                          \
        if (has1) {                                                \
            e1 = *(const float4v*)(rp + ge1);                      \
            o1 = *(const float4v*)(rp + go1);                      \
        }                                                          \
    } while (0)

#define WRITE_ROW(sb) do {                                         \
        char* wb0 = (sb) + (1 + 4 * w40) * PIX_STRIDE + cp0 * 4;   \
        *(unsigned*)(wb0                  ) = pack2(e0[0], o0[0]); \
        *(unsigned*)(wb0 +     PIX_STRIDE ) = pack2(e0[1], o0[1]); \
        *(unsigned*)(wb0 + 2 * PIX_STRIDE ) = pack2(e0[2], o0[2]); \
        *(unsigned*)(wb0 + 3 * PIX_STRIDE ) = pack2(e0[3], o0[3]); \
        if (has1) {                                                \
            char* wb1 = (sb) + (1 + 4 * w41) * PIX_STRIDE + cp1 * 4; \
            *(unsigned*)(wb1                  ) = pack2(e1[0], o1[0]); \
            *(unsigned*)(wb1 +     PIX_STRIDE ) = pack2(e1[1], o1[1]); \
            *(unsigned*)(wb1 + 2 * PIX_STRIDE ) = pack2(e1[2], o1[2]); \
            *(unsigned*)(wb1 + 3 * PIX_STRIDE ) = pack2(e1[3], o1[3]); \
        }                                                          \
        if (tid < 8) {  /* zero the two w-halo pixels (px 0 and 225) */ \
            int px = (tid < 4) ? 0 : (RING_PX - 1);                \
            *(short8*)((sb) + px * PIX_STRIDE + (tid & 3) * 16) = z8; \
        }                                                          \
    } while (0)

#define ZERO_ROW(sb) do {                                          \
        for (int i = tid; i < ROW_BYTES / 16; i += NTHR)           \
            *(short8*)((sb) + i * 16) = z8;                        \
    } while (0)

    // ===== Prologue: fill ring with rows h1-1, h1, h1+1 =====
#pragma unroll
    for (int j = 0; j < 3; ++j) {
        int hh = h1 - 1 + j;
        char* sb = (j == 0) ? ring0 : (j == 1) ? ring1 : ring2;
        if (hh >= 0 && hh < HH) {   // block-uniform
            LOAD_ROW(hh);
            WRITE_ROW(sb);
        } else {
            ZERO_ROW(sb);
        }
    }
    __syncthreads();

    // ===== Main loop: rA = row h-1, rB = h, rC = h+1; write h+2 over rA =====
    char *rA = ring0, *rB = ring1, *rC = ring2;
    const int pcol = col * PIX_STRIDE + khalf * 16;

    for (int h = h1; h < h1 + STRIPE; ++h) {
        const int hh = h + 2;
        const bool do_pref = (hh <= h1 + STRIPE);   // last needed row = h1+STRIPE
        const bool validrow = do_pref && (hh < HH); // block-uniform

        // Phase 1: issue next row's global loads (waits land in Phase 4, after MFMA)
        if (validrow) LOAD_ROW(hh);

        // Phase 2: compute output row h; wave w owns px [32w, 32w+32)
        if (wid < 7) {
            const int px0 = wid * 32;
            f32x16 acc = biasv;   // bias folded into accumulator init
            const int pb = px0 * PIX_STRIDE + pcol;
#pragma unroll
            for (int rs = 0; rs < 9; ++rs) {
                const int r = rs / 3, s = rs - 3 * r;
                const char* rb = (r == 0) ? rA : (r == 1) ? rB : rC;
                const int addr = pb + s * PIX_STRIDE;
#pragma unroll
                for (int ch = 0; ch < 2; ++ch) {
                    short8 bfrag = *(const short8*)(rb + addr + ch * 32);
                    acc = __builtin_amdgcn_mfma_f32_32x32x16_bf16(
                        wfrag[rs * 2 + ch], bfrag, acc, 0, 0, 0);
                }
            }
            const int ybase = n * C_OUT * HW + h * WW + px0 + col;
#pragma unroll
            for (int i = 0; i < 16; ++i) {
                int ko = (i & 3) + 8 * (i >> 2) + 4 * khalf;
                Y[ybase + ko * HW] = acc[i];
            }
        }

        // Phase 3: all reads of rA done before it is overwritten
        __syncthreads();

        // Phase 4: convert + write row h+2 into the expired slot
        if (validrow) {
            WRITE_ROW(rA);
        } else if (do_pref) {
            ZERO_ROW(rA);   // image bottom edge
        }
        __syncthreads();

        // rotate ring
        char* t = rA; rA = rB; rB = rC; rC = t;
    }
#undef LOAD_ROW
#undef WRITE_ROW
#undef ZERO_ROW
}

extern "C" void kernel_launch(void* const* d_in, const int* in_sizes, int n_in,
                              void* d_out, int out_size, void* d_ws, size_t ws_size,
                              hipStream_t stream) {
    const float* X = (const float*)d_in[0];
    const float* W = (const float*)d_in[1];
    const float* B = (const float*)d_in[2];
    float* Y = (float*)d_out;
    // 512 blocks = 32 images x 16 stripes; 2 resident per CU (LDS 108.5KB/CU)
    conv3x3_rows<<<dim3(512), dim3(NTHR), 0, stream>>>(X, W, B, Y);
}